// Round 1
// baseline (355.691 us; speedup 1.0000x reference)
//
#include <hip/hip_runtime.h>
#include <hip/hip_bf16.h>
#include <math.h>

#define BB 16
#define SS 2048
#define DD 512
#define NDOCS 200000
#define TOPK 5
#define EPSN 1e-12f
#define NEG_INF (-3.0e38f)

#define TILE_N 256
#define KC 32
#define NCHUNK (DD / KC)          // 16
#define NBLK3 ((NDOCS + TILE_N - 1) / TILE_N)   // 782

typedef short s16x8 __attribute__((ext_vector_type(8)));
typedef float f32x4 __attribute__((ext_vector_type(4)));

__device__ __forceinline__ short f2bf(float f) {
    __bf16 b = (__bf16)f;
    short s;
    __builtin_memcpy(&s, &b, 2);
    return s;
}

__device__ __forceinline__ void gload_lds16(const void* g, void* l) {
    __builtin_amdgcn_global_load_lds(
        (const __attribute__((address_space(1))) void*)g,
        (__attribute__((address_space(3))) void*)l, 16, 0, 0);
}

// ---------------- K1: partial mean pool ----------------
// grid (64, 16) blocks of 128 threads; partial[64][16][512]
__global__ __launch_bounds__(128) void k1_mean_partial(
    const float* __restrict__ hs, float* __restrict__ partial) {
    int b = blockIdx.y, sc = blockIdx.x;
    int t = threadIdx.x;   // float4 column 0..127
    const float4* src = (const float4*)(hs + (size_t)(b * SS + sc * 32) * DD);
    float4 acc = {0.f, 0.f, 0.f, 0.f};
    for (int s = 0; s < 32; ++s) {
        float4 v = src[(size_t)s * 128 + t];
        acc.x += v.x; acc.y += v.y; acc.z += v.z; acc.w += v.w;
    }
    ((float4*)partial)[(size_t)(sc * BB + b) * 128 + t] = acc;
}

// ---------------- K2: query = mean @ Wq^T + bq, l2norm ----------------
// grid 16 blocks of 256
__global__ __launch_bounds__(256) void k2_query(
    const float* __restrict__ partial, const float* __restrict__ Wq,
    const float* __restrict__ bq, float* __restrict__ qout) {
    int b = blockIdx.x, t = threadIdx.x;
    __shared__ float meanv[DD];
    __shared__ float qtmp[DD];
    __shared__ float red[4];
    for (int j = t; j < DD; j += 256) {
        float s = 0.f;
        for (int c = 0; c < 64; ++c) s += partial[(size_t)(c * BB + b) * DD + j];
        meanv[j] = s * (1.0f / 2048.0f);
    }
    __syncthreads();
    for (int j = t; j < DD; j += 256) {
        float acc = bq[j];
        const float4* wr = (const float4*)(Wq + (size_t)j * DD);
        const float4* mv = (const float4*)meanv;
        for (int k4 = 0; k4 < DD / 4; ++k4) {
            float4 w = wr[k4], m = mv[k4];
            acc = fmaf(w.x, m.x, acc); acc = fmaf(w.y, m.y, acc);
            acc = fmaf(w.z, m.z, acc); acc = fmaf(w.w, m.w, acc);
        }
        qtmp[j] = acc;
    }
    __syncthreads();
    float ss = 0.f;
    for (int j = t; j < DD; j += 256) ss += qtmp[j] * qtmp[j];
    for (int m = 1; m < 64; m <<= 1) ss += __shfl_xor(ss, m);
    if ((t & 63) == 0) red[t >> 6] = ss;
    __syncthreads();
    float tot = red[0] + red[1] + red[2] + red[3];
    float inv = 1.0f / fmaxf(sqrtf(tot), EPSN);
    for (int j = t; j < DD; j += 256) qout[(size_t)b * DD + j] = qtmp[j] * inv;
}

// ---------------- K3: corpus scan + per-block top-5 ----------------
// grid NBLK3 blocks of 256 (4 waves). LDS 64KB double-buffered doc tile.
__global__ __launch_bounds__(256) void k3_scores(
    const float* __restrict__ docs, const float* __restrict__ qv,
    float* __restrict__ cand_s, int* __restrict__ cand_i) {
    __shared__ float4 Et[2][TILE_N * 8];   // [buf][n*8 + slot] : 2 x 32KB

    int t = threadIdx.x;
    int w = t >> 6, lane = t & 63;
    int ln = lane & 15, bg = lane >> 4;
    int blk = blockIdx.x;
    long tileBase = (long)blk * TILE_N;

    const float4* q4 = (const float4*)qv;   // [b*128 + k4]

    // stage chunk c into buffer buf (8 global_load_lds per wave)
    auto stage = [&](int c, int buf) {
#pragma unroll
        for (int j = 0; j < 8; ++j) {
            int u = ((w * 8 + j) << 6) + lane;  // linear float4 unit
            int n = u >> 3, slot = u & 7;
            int k4src = slot ^ (n & 7);
            long row = tileBase + n;
            if (row > NDOCS - 1) row = NDOCS - 1;
            const float* g = docs + row * (long)DD + c * KC + k4src * 4;
            gload_lds16(g, (void*)&Et[buf][(w * 8 + j) * 64]);
        }
    };

    float acc[4][4];
    float nrm[4];
#pragma unroll
    for (int i = 0; i < 4; ++i) {
        nrm[i] = 0.f;
#pragma unroll
        for (int j = 0; j < 4; ++j) acc[i][j] = 0.f;
    }

    stage(0, 0);
    for (int c = 0; c < NCHUNK; ++c) {
        __syncthreads();                       // stage(c) complete (all waves)
        if (c + 1 < NCHUNK) stage(c + 1, (c + 1) & 1);  // overlap with compute
        const float4* Eb = &Et[c & 1][0];
        int c8 = c * 8;
#pragma unroll
        for (int k4 = 0; k4 < 8; ++k4) {
            float4 q0 = q4[(bg * 4 + 0) * 128 + c8 + k4];
            float4 q1 = q4[(bg * 4 + 1) * 128 + c8 + k4];
            float4 q2 = q4[(bg * 4 + 2) * 128 + c8 + k4];
            float4 q3 = q4[(bg * 4 + 3) * 128 + c8 + k4];
#pragma unroll
            for (int i = 0; i < 4; ++i) {
                int n = (w << 6) + ln + (i << 4);
                float4 e = Eb[(n << 3) + (k4 ^ (ln & 7))];
                nrm[i]    = fmaf(e.x, e.x, fmaf(e.y, e.y, fmaf(e.z, e.z, fmaf(e.w, e.w, nrm[i]))));
                acc[i][0] = fmaf(e.x, q0.x, fmaf(e.y, q0.y, fmaf(e.z, q0.z, fmaf(e.w, q0.w, acc[i][0]))));
                acc[i][1] = fmaf(e.x, q1.x, fmaf(e.y, q1.y, fmaf(e.z, q1.z, fmaf(e.w, q1.w, acc[i][1]))));
                acc[i][2] = fmaf(e.x, q2.x, fmaf(e.y, q2.y, fmaf(e.z, q2.z, fmaf(e.w, q2.w, acc[i][2]))));
                acc[i][3] = fmaf(e.x, q3.x, fmaf(e.y, q3.y, fmaf(e.z, q3.z, fmaf(e.w, q3.w, acc[i][3]))));
            }
        }
    }

    // scoreboard: S[b][n] over Et[0] (16KB)
    float* Sb = (float*)&Et[0][0];
#pragma unroll
    for (int i = 0; i < 4; ++i) {
        int n = (w << 6) + ln + (i << 4);
        float inv = 1.0f / fmaxf(sqrtf(nrm[i]), EPSN);
#pragma unroll
        for (int j = 0; j < 4; ++j)
            Sb[(bg * 4 + j) * TILE_N + n] = acc[i][j] * inv;
    }
    __syncthreads();

    // each wave: 4 batch rows, 5-round wave argmax with masking
    for (int jj = 0; jj < 4; ++jj) {
        int b = w * 4 + jj;
        float v[4]; int nn[4];
#pragma unroll
        for (int m = 0; m < 4; ++m) {
            int n = lane + m * 64;
            nn[m] = n;
            v[m] = (tileBase + n < NDOCS) ? Sb[b * TILE_N + n] : NEG_INF;
        }
        for (int r = 0; r < TOPK; ++r) {
            float bv = v[0]; int bi = nn[0];
#pragma unroll
            for (int m = 1; m < 4; ++m)
                if (v[m] > bv || (v[m] == bv && nn[m] < bi)) { bv = v[m]; bi = nn[m]; }
            for (int mm = 1; mm < 64; mm <<= 1) {
                float ov = __shfl_xor(bv, mm);
                int   oi = __shfl_xor(bi, mm);
                if (ov > bv || (ov == bv && oi < bi)) { bv = ov; bi = oi; }
            }
            if (lane == 0) {
                cand_s[((long)blk * BB + b) * TOPK + r] = bv;
                cand_i[((long)blk * BB + b) * TOPK + r] = (int)(tileBase + bi);
            }
#pragma unroll
            for (int m = 0; m < 4; ++m)
                if (nn[m] == bi) v[m] = NEG_INF;
        }
    }
}

// ---------------- K4: merge top-5, softmax, context, ctx-logit ----------------
// grid 16 blocks of 256
__global__ __launch_bounds__(256) void k4_finalize(
    const float* __restrict__ docs, const float* __restrict__ Wg,
    const float* __restrict__ bgt, const float* __restrict__ cand_s,
    const int* __restrict__ cand_i, float* __restrict__ ctx,
    float* __restrict__ ctxb, float* __restrict__ outp) {
    int b = blockIdx.x, t = threadIdx.x;
    __shared__ float sv[256];
    __shared__ int   si[256];
    __shared__ float topv[TOPK];
    __shared__ int   topi[TOPK];
    __shared__ float ctxLds[DD];
    __shared__ float red[4];
    __shared__ float nrm5[TOPK];
    __shared__ float wts[TOPK];

    float lv[TOPK]; int li[TOPK];
#pragma unroll
    for (int r = 0; r < TOPK; ++r) { lv[r] = NEG_INF; li[r] = 0x7fffffff; }

    for (int j = t; j < NBLK3 * TOPK; j += 256) {
        int blk = j / TOPK, r = j - blk * TOPK;
        float s = cand_s[(long)blk * (BB * TOPK) + b * TOPK + r];
        int  di = cand_i[(long)blk * (BB * TOPK) + b * TOPK + r];
        if (s > lv[TOPK - 1] || (s == lv[TOPK - 1] && di < li[TOPK - 1])) {
            lv[TOPK - 1] = s; li[TOPK - 1] = di;
#pragma unroll
            for (int k = TOPK - 1; k > 0; --k) {
                if (lv[k] > lv[k - 1] || (lv[k] == lv[k - 1] && li[k] < li[k - 1])) {
                    float tv = lv[k]; lv[k] = lv[k - 1]; lv[k - 1] = tv;
                    int   ti = li[k]; li[k] = li[k - 1]; li[k - 1] = ti;
                }
            }
        }
    }

    int p = 0;
    for (int r = 0; r < TOPK; ++r) {
        float hv = (p < TOPK) ? lv[p] : NEG_INF;
        int   hi = (p < TOPK) ? li[p] : 0x7fffffff;
        sv[t] = hv; si[t] = hi;
        __syncthreads();
        for (int off = 128; off > 0; off >>= 1) {
            if (t < off) {
                float ov = sv[t + off]; int oi = si[t + off];
                if (ov > sv[t] || (ov == sv[t] && oi < si[t])) { sv[t] = ov; si[t] = oi; }
            }
            __syncthreads();
        }
        if (t == 0) { topv[r] = sv[0]; topi[r] = si[0]; }
        __syncthreads();
        if (hv == topv[r] && hi == topi[r]) ++p;
        __syncthreads();
    }

    // norms of the 5 selected docs
    for (int r = 0; r < TOPK; ++r) {
        const float* dr = docs + (size_t)topi[r] * DD;
        float s2 = dr[t] * dr[t] + dr[t + 256] * dr[t + 256];
        for (int m = 1; m < 64; m <<= 1) s2 += __shfl_xor(s2, m);
        if ((t & 63) == 0) red[t >> 6] = s2;
        __syncthreads();
        if (t == 0) nrm5[r] = sqrtf(red[0] + red[1] + red[2] + red[3]);
        __syncthreads();
    }

    if (t == 0) {
        float m = topv[0];
        float e[TOPK], s = 0.f;
#pragma unroll
        for (int r = 0; r < TOPK; ++r) { e[r] = expf(topv[r] - m); s += e[r]; }
#pragma unroll
        for (int r = 0; r < TOPK; ++r) wts[r] = e[r] / s;
    }
    __syncthreads();

    for (int j = t; j < DD; j += 256) {
        float c = 0.f;
#pragma unroll
        for (int r = 0; r < TOPK; ++r)
            c += wts[r] * docs[(size_t)topi[r] * DD + j] / fmaxf(nrm5[r], EPSN);
        ctxLds[j] = c;
        ctx[(size_t)b * DD + j] = c;
    }
    __syncthreads();

    for (int j = t; j < DD; j += 256) {
        float acc = bgt[j];
        const float4* wr = (const float4*)(Wg + (size_t)j * (2 * DD) + DD);
        const float4* cv = (const float4*)ctxLds;
        for (int k4 = 0; k4 < DD / 4; ++k4) {
            float4 wv = wr[k4], mv = cv[k4];
            acc = fmaf(wv.x, mv.x, acc); acc = fmaf(wv.y, mv.y, acc);
            acc = fmaf(wv.z, mv.z, acc); acc = fmaf(wv.w, mv.w, acc);
        }
        ctxb[(size_t)b * DD + j] = acc;
    }

    if (t < TOPK) {
        outp[b * TOPK + t] = topv[t];
        outp[BB * TOPK + b * TOPK + t] = (float)topi[t];   // indices as float
    }
}

// ---------------- K5: bf16 MFMA gate GEMM + fused epilogue ----------------
// C[row,dout] = sum_k h[row,k]*Wg[dout,k]; grid (256, 4), 256 threads
#define BM 128
#define BN 128
#define BK 32
__global__ __launch_bounds__(256) void k5_gemm_fused(
    const float* __restrict__ hs, const float* __restrict__ Wg,
    const float* __restrict__ ctx, const float* __restrict__ ctxb,
    float* __restrict__ outF) {
    __shared__ short At[BM][BK];
    __shared__ short Bt[BN][BK];
    __shared__ float ctxLds[BN];
    __shared__ float ctxbLds[BN];

    int bm = blockIdx.x, bn = blockIdx.y;
    int t = threadIdx.x;
    int wv = t >> 6, lane = t & 63, ln = lane & 15, kg = lane >> 4;
    int wm = (wv >> 1) * 64, wn = (wv & 1) * 64;
    int bbatch = bm >> 4;   // bm*128 / 2048

    for (int j = t; j < BN; j += 256) {
        ctxLds[j]  = ctx[(size_t)bbatch * DD + bn * BN + j];
        ctxbLds[j] = ctxb[(size_t)bbatch * DD + bn * BN + j];
    }

    float4 pf[4][2];
    auto gload = [&](int kt) {
#pragma unroll
        for (int uu = 0; uu < 4; ++uu) {
            int u = t + uu * 256;
            int isB = u >> 9;
            int vix = u & 511;
            int row = (vix >> 2) & 127, slot = vix & 3;
            const float* src = isB
                ? (Wg + (size_t)(bn * BN + row) * (2 * DD) + kt * BK + slot * 8)
                : (hs + (size_t)(bm * BM + row) * DD + kt * BK + slot * 8);
            pf[uu][0] = ((const float4*)src)[0];
            pf[uu][1] = ((const float4*)src)[1];
        }
    };
    auto cvtwrite = [&]() {
#pragma unroll
        for (int uu = 0; uu < 4; ++uu) {
            int u = t + uu * 256;
            int isB = u >> 9;
            int vix = u & 511;
            int row = (vix >> 2) & 127, slot = vix & 3;
            int sl = slot ^ ((row >> 1) & 3);
            s16x8 cv;
            cv[0] = f2bf(pf[uu][0].x); cv[1] = f2bf(pf[uu][0].y);
            cv[2] = f2bf(pf[uu][0].z); cv[3] = f2bf(pf[uu][0].w);
            cv[4] = f2bf(pf[uu][1].x); cv[5] = f2bf(pf[uu][1].y);
            cv[6] = f2bf(pf[uu][1].z); cv[7] = f2bf(pf[uu][1].w);
            short* base = isB ? &Bt[0][0] : &At[0][0];
            *(s16x8*)(base + row * BK + sl * 8) = cv;
        }
    };

    f32x4 accv[4][4];
#pragma unroll
    for (int i = 0; i < 4; ++i)
#pragma unroll
        for (int j = 0; j < 4; ++j) accv[i][j] = (f32x4){0.f, 0.f, 0.f, 0.f};

    gload(0);
    for (int kt = 0; kt < DD / BK; ++kt) {
        __syncthreads();
        cvtwrite();
        if (kt + 1 < DD / BK) gload(kt + 1);
        __syncthreads();
        s16x8 af[4], bfr[4];
#pragma unroll
        for (int mi = 0; mi < 4; ++mi) {
            int row = wm + mi * 16 + ln;
            int sl = kg ^ ((row >> 1) & 3);
            af[mi] = *(const s16x8*)&At[row][sl * 8];
        }
#pragma unroll
        for (int nj = 0; nj < 4; ++nj) {
            int row = wn + nj * 16 + ln;
            int sl = kg ^ ((row >> 1) & 3);
            bfr[nj] = *(const s16x8*)&Bt[row][sl * 8];
        }
#pragma unroll
        for (int mi = 0; mi < 4; ++mi)
#pragma unroll
            for (int nj = 0; nj < 4; ++nj)
                accv[mi][nj] = __builtin_amdgcn_mfma_f32_16x16x32_bf16(
                    af[mi], bfr[nj], accv[mi][nj], 0, 0, 0);
    }

    // epilogue: gate = sigmoid(acc + ctxb); fused = g*h + (1-g)*ctx
#pragma unroll
    for (int mi = 0; mi < 4; ++mi)
#pragma unroll
        for (int nj = 0; nj < 4; ++nj)
#pragma unroll
            for (int r = 0; r < 4; ++r) {
                int ri = wm + mi * 16 + kg * 4 + r;
                int ci = wn + nj * 16 + ln;
                size_t grow = (size_t)bm * BM + ri;
                int gcol = bn * BN + ci;
                float logit = accv[mi][nj][r] + ctxbLds[ci];
                float g = 1.0f / (1.0f + expf(-logit));
                float h = hs[grow * DD + gcol];
                float cx = ctxLds[ci];
                outF[grow * DD + gcol] = g * h + (1.0f - g) * cx;
            }
}

// ---------------- launch ----------------
extern "C" void kernel_launch(void* const* d_in, const int* in_sizes, int n_in,
                              void* d_out, int out_size, void* d_ws, size_t ws_size,
                              hipStream_t stream) {
    const float* hs   = (const float*)d_in[0];
    const float* docs = (const float*)d_in[1];
    const float* Wq   = (const float*)d_in[2];
    const float* bq   = (const float*)d_in[3];
    const float* Wg   = (const float*)d_in[4];
    const float* bgt  = (const float*)d_in[5];
    float* outp = (float*)d_out;
    float* ws = (float*)d_ws;

    float* partial = ws;                               // 64*16*512 = 524288
    float* qv      = partial + 64 * BB * DD;           // 8192
    float* ctx     = qv + BB * DD;                     // 8192
    float* ctxb    = ctx + BB * DD;                    // 8192
    float* cand_s  = ctxb + BB * DD;                   // 782*80 = 62560
    int*   cand_i  = (int*)(cand_s + NBLK3 * BB * TOPK);

    k1_mean_partial<<<dim3(64, 16), 128, 0, stream>>>(hs, partial);
    k2_query<<<BB, 256, 0, stream>>>(partial, Wq, bq, qv);
    k3_scores<<<NBLK3, 256, 0, stream>>>(docs, qv, cand_s, cand_i);
    k4_finalize<<<BB, 256, 0, stream>>>(docs, Wg, bgt, cand_s, cand_i, ctx, ctxb, outp);
    k5_gemm_fused<<<dim3(256, 4), 256, 0, stream>>>(hs, Wg, ctx, ctxb,
                                                    outp + 2 * BB * TOPK);
}

// Round 2
// 309.179 us; speedup vs baseline: 1.1504x; 1.1504x over previous
//
#include <hip/hip_runtime.h>
#include <hip/hip_bf16.h>
#include <math.h>

#define BB 16
#define SS 2048
#define DD 512
#define NDOCS 200000
#define TOPK 5
#define EPSN 1e-12f
#define NEG_INF (-3.0e38f)

#define TILE_N 128
#define KC 64
#define NCHUNK (DD / KC)                          // 8
#define NBLK3 ((NDOCS + TILE_N - 1) / TILE_N)     // 1563

typedef short s16x8 __attribute__((ext_vector_type(8)));
typedef float f32x4 __attribute__((ext_vector_type(4)));

__device__ __forceinline__ short f2bf(float f) {
    __bf16 b = (__bf16)f;
    short s;
    __builtin_memcpy(&s, &b, 2);
    return s;
}

__device__ __forceinline__ void gload_lds16(const void* g, void* l) {
    __builtin_amdgcn_global_load_lds(
        (const __attribute__((address_space(1))) void*)g,
        (__attribute__((address_space(3))) void*)l, 16, 0, 0);
}

// ---------------- K1: partial mean pool: partial[32][16][512] ----------------
__global__ __launch_bounds__(128) void k1_mean_partial(
    const float* __restrict__ hs, float* __restrict__ partial) {
    int b = blockIdx.y, sc = blockIdx.x;           // sc 0..31, 64 rows each
    int t = threadIdx.x;                            // float4 column 0..127
    const float4* src = (const float4*)(hs + (size_t)(b * SS + sc * 64) * DD);
    float4 acc = {0.f, 0.f, 0.f, 0.f};
    for (int s = 0; s < 64; ++s) {
        float4 v = src[(size_t)s * 128 + t];
        acc.x += v.x; acc.y += v.y; acc.z += v.z; acc.w += v.w;
    }
    ((float4*)partial)[(size_t)(sc * BB + b) * 128 + t] = acc;
}

// ---------------- K1b: reduce partials -> mean[16][512] ----------------
__global__ __launch_bounds__(128) void k1b_mean_reduce(
    const float* __restrict__ partial, float* __restrict__ mean) {
    int b = blockIdx.y, jc = blockIdx.x;           // jc 0..3
    int j = jc * 128 + threadIdx.x;
    float s = 0.f;
    for (int c = 0; c < 32; ++c) s += partial[(size_t)(c * BB + b) * DD + j];
    mean[(size_t)b * DD + j] = s * (1.0f / 2048.0f);
}

// ---------------- K2a: qtmp[b][j] = mean[b] . Wq[j] + bq[j] ----------------
// grid (32, 16), 256 threads: 16 rows/block, 16 lanes/row
__global__ __launch_bounds__(256) void k2a_q_gemv(
    const float* __restrict__ mean, const float* __restrict__ Wq,
    const float* __restrict__ bq, float* __restrict__ qtmp) {
    int b = blockIdx.y, jc = blockIdx.x;
    int t = threadIdx.x;
    int r = t >> 4, c = t & 15;
    int row = jc * 16 + r;
    const float4* wr = (const float4*)(Wq + (size_t)row * DD);
    const float4* mv = (const float4*)(mean + (size_t)b * DD);
    float acc = 0.f;
#pragma unroll
    for (int it = 0; it < 8; ++it) {
        int k4 = c + it * 16;
        float4 w = wr[k4], m = mv[k4];
        acc = fmaf(w.x, m.x, acc); acc = fmaf(w.y, m.y, acc);
        acc = fmaf(w.z, m.z, acc); acc = fmaf(w.w, m.w, acc);
    }
#pragma unroll
    for (int m = 1; m < 16; m <<= 1) acc += __shfl_xor(acc, m);
    if (c == 0) qtmp[(size_t)b * DD + row] = acc + bq[row];
}

// ---------------- K2b: l2-normalize qtmp -> qv ----------------
__global__ __launch_bounds__(256) void k2b_q_norm(
    const float* __restrict__ qtmp, float* __restrict__ qv) {
    int b = blockIdx.x, t = threadIdx.x;
    __shared__ float red[4];
    float a0 = qtmp[(size_t)b * DD + t];
    float a1 = qtmp[(size_t)b * DD + t + 256];
    float ss = a0 * a0 + a1 * a1;
#pragma unroll
    for (int m = 1; m < 64; m <<= 1) ss += __shfl_xor(ss, m);
    if ((t & 63) == 0) red[t >> 6] = ss;
    __syncthreads();
    float inv = 1.0f / fmaxf(sqrtf(red[0] + red[1] + red[2] + red[3]), EPSN);
    qv[(size_t)b * DD + t] = a0 * inv;
    qv[(size_t)b * DD + t + 256] = a1 * inv;
}

// ---------------- K3: corpus scan + per-block top-5 ----------------
// grid NBLK3 blocks of 256 (4 waves). Tile 128 docs x 64 dims, dbuf, 64KB LDS.
__global__ __launch_bounds__(256) void k3_scores(
    const float* __restrict__ docs, const float* __restrict__ qv,
    float* __restrict__ cand_s, int* __restrict__ cand_i) {
    __shared__ float4 Et[2][TILE_N * 16];   // [buf][n*16 + slot] : 2 x 32KB

    int t = threadIdx.x;
    int w = t >> 6, lane = t & 63;
    int ln = lane & 15, bg = lane >> 4;
    int blk = blockIdx.x;
    long tileBase = (long)blk * TILE_N;

    const float4* q4 = (const float4*)qv;   // [b*128 + c*16 + k4]

    // stage chunk c (KC=64 floats = 16 float4 per row) into buffer buf
    auto stage = [&](int c, int buf) {
#pragma unroll
        for (int j = 0; j < 8; ++j) {
            int u = ((w * 8 + j) << 6) + lane;  // linear float4 unit 0..2047
            int n = u >> 4, slot = u & 15;
            int k4src = slot ^ (n & 15);
            long row = tileBase + n;
            if (row > NDOCS - 1) row = NDOCS - 1;
            const float* g = docs + row * (long)DD + c * KC + k4src * 4;
            gload_lds16(g, (void*)&Et[buf][(w * 8 + j) * 64]);
        }
    };

    float acc[2][4];
    float nrm[2];
#pragma unroll
    for (int i = 0; i < 2; ++i) {
        nrm[i] = 0.f;
#pragma unroll
        for (int j = 0; j < 4; ++j) acc[i][j] = 0.f;
    }

    stage(0, 0);
    for (int c = 0; c < NCHUNK; ++c) {
        __syncthreads();                       // stage(c) drained at barrier
        if (c + 1 < NCHUNK) stage(c + 1, (c + 1) & 1);  // prefetch overlaps
        const float4* Eb = &Et[c & 1][0];
        int c16 = c * 16;
#pragma unroll
        for (int k4 = 0; k4 < 16; ++k4) {
            float4 q0 = q4[(bg * 4 + 0) * 128 + c16 + k4];
            float4 q1 = q4[(bg * 4 + 1) * 128 + c16 + k4];
            float4 q2 = q4[(bg * 4 + 2) * 128 + c16 + k4];
            float4 q3 = q4[(bg * 4 + 3) * 128 + c16 + k4];
#pragma unroll
            for (int i = 0; i < 2; ++i) {
                int n = (w << 5) + ln + (i << 4);
                float4 e = Eb[(n << 4) + (k4 ^ (n & 15))];
                nrm[i]    = fmaf(e.x, e.x, fmaf(e.y, e.y, fmaf(e.z, e.z, fmaf(e.w, e.w, nrm[i]))));
                acc[i][0] = fmaf(e.x, q0.x, fmaf(e.y, q0.y, fmaf(e.z, q0.z, fmaf(e.w, q0.w, acc[i][0]))));
                acc[i][1] = fmaf(e.x, q1.x, fmaf(e.y, q1.y, fmaf(e.z, q1.z, fmaf(e.w, q1.w, acc[i][1]))));
                acc[i][2] = fmaf(e.x, q2.x, fmaf(e.y, q2.y, fmaf(e.z, q2.z, fmaf(e.w, q2.w, acc[i][2]))));
                acc[i][3] = fmaf(e.x, q3.x, fmaf(e.y, q3.y, fmaf(e.z, q3.z, fmaf(e.w, q3.w, acc[i][3]))));
            }
        }
    }

    // scoreboard S[b][n] over Et[0] (16x128 f32 = 8KB)
    float* Sb = (float*)&Et[0][0];
    __syncthreads();
#pragma unroll
    for (int i = 0; i < 2; ++i) {
        int n = (w << 5) + ln + (i << 4);
        float inv = 1.0f / fmaxf(sqrtf(nrm[i]), EPSN);
#pragma unroll
        for (int j = 0; j < 4; ++j)
            Sb[(bg * 4 + j) * TILE_N + n] = acc[i][j] * inv;
    }
    __syncthreads();

    // each wave handles 4 batch rows: 5-round argmax with masking
    for (int jj = 0; jj < 4; ++jj) {
        int b = w * 4 + jj;
        float v[2]; int nn[2];
#pragma unroll
        for (int m = 0; m < 2; ++m) {
            int n = lane + m * 64;
            nn[m] = n;
            v[m] = (tileBase + n < NDOCS) ? Sb[b * TILE_N + n] : NEG_INF;
        }
        for (int r = 0; r < TOPK; ++r) {
            float bv = v[0]; int bi = nn[0];
            if (v[1] > bv || (v[1] == bv && nn[1] < bi)) { bv = v[1]; bi = nn[1]; }
#pragma unroll
            for (int mm = 1; mm < 64; mm <<= 1) {
                float ov = __shfl_xor(bv, mm);
                int   oi = __shfl_xor(bi, mm);
                if (ov > bv || (ov == bv && oi < bi)) { bv = ov; bi = oi; }
            }
            if (lane == 0) {
                cand_s[((long)blk * BB + b) * TOPK + r] = bv;
                cand_i[((long)blk * BB + b) * TOPK + r] = (int)(tileBase + bi);
            }
#pragma unroll
            for (int m = 0; m < 2; ++m)
                if (nn[m] == bi) v[m] = NEG_INF;
        }
    }
}

// ---------------- K4a: merge top-5, softmax, context, outputs ----------------
__global__ __launch_bounds__(256) void k4a_topk_ctx(
    const float* __restrict__ docs, const float* __restrict__ cand_s,
    const int* __restrict__ cand_i, float* __restrict__ ctx,
    float* __restrict__ outp) {
    int b = blockIdx.x, t = threadIdx.x;
    __shared__ float sv[256];
    __shared__ int   si[256];
    __shared__ float topv[TOPK];
    __shared__ int   topi[TOPK];
    __shared__ float red[4];
    __shared__ float nrm5[TOPK];
    __shared__ float wts[TOPK];

    float lv[TOPK]; int li[TOPK];
#pragma unroll
    for (int r = 0; r < TOPK; ++r) { lv[r] = NEG_INF; li[r] = 0x7fffffff; }

    for (int j = t; j < NBLK3 * TOPK; j += 256) {
        int blk = j / TOPK, r = j - blk * TOPK;
        float s = cand_s[(long)blk * (BB * TOPK) + b * TOPK + r];
        int  di = cand_i[(long)blk * (BB * TOPK) + b * TOPK + r];
        if (s > lv[TOPK - 1] || (s == lv[TOPK - 1] && di < li[TOPK - 1])) {
            lv[TOPK - 1] = s; li[TOPK - 1] = di;
#pragma unroll
            for (int k = TOPK - 1; k > 0; --k) {
                if (lv[k] > lv[k - 1] || (lv[k] == lv[k - 1] && li[k] < li[k - 1])) {
                    float tv = lv[k]; lv[k] = lv[k - 1]; lv[k - 1] = tv;
                    int   ti = li[k]; li[k] = li[k - 1]; li[k - 1] = ti;
                }
            }
        }
    }

    int p = 0;
    for (int r = 0; r < TOPK; ++r) {
        float hv = (p < TOPK) ? lv[p] : NEG_INF;
        int   hi = (p < TOPK) ? li[p] : 0x7fffffff;
        sv[t] = hv; si[t] = hi;
        __syncthreads();
        for (int off = 128; off > 0; off >>= 1) {
            if (t < off) {
                float ov = sv[t + off]; int oi = si[t + off];
                if (ov > sv[t] || (ov == sv[t] && oi < si[t])) { sv[t] = ov; si[t] = oi; }
            }
            __syncthreads();
        }
        if (t == 0) { topv[r] = sv[0]; topi[r] = si[0]; }
        __syncthreads();
        if (hv == topv[r] && hi == topi[r]) ++p;
        __syncthreads();
    }

    for (int r = 0; r < TOPK; ++r) {
        const float* dr = docs + (size_t)topi[r] * DD;
        float s2 = dr[t] * dr[t] + dr[t + 256] * dr[t + 256];
#pragma unroll
        for (int m = 1; m < 64; m <<= 1) s2 += __shfl_xor(s2, m);
        if ((t & 63) == 0) red[t >> 6] = s2;
        __syncthreads();
        if (t == 0) nrm5[r] = sqrtf(red[0] + red[1] + red[2] + red[3]);
        __syncthreads();
    }

    if (t == 0) {
        float m = topv[0];
        float e[TOPK], s = 0.f;
#pragma unroll
        for (int r = 0; r < TOPK; ++r) { e[r] = expf(topv[r] - m); s += e[r]; }
#pragma unroll
        for (int r = 0; r < TOPK; ++r) wts[r] = e[r] / s;
    }
    __syncthreads();

    for (int j = t; j < DD; j += 256) {
        float c = 0.f;
#pragma unroll
        for (int r = 0; r < TOPK; ++r)
            c += wts[r] * docs[(size_t)topi[r] * DD + j] / fmaxf(nrm5[r], EPSN);
        ctx[(size_t)b * DD + j] = c;
    }

    if (t < TOPK) {
        outp[b * TOPK + t] = topv[t];
        outp[BB * TOPK + b * TOPK + t] = (float)topi[t];   // indices as float
    }
}

// ---------------- K4b: ctxb[b][j] = ctx[b] . Wg[j, 512:1024] + bg[j] --------
__global__ __launch_bounds__(256) void k4b_ctxb_gemv(
    const float* __restrict__ ctx, const float* __restrict__ Wg,
    const float* __restrict__ bgt, float* __restrict__ ctxb) {
    int b = blockIdx.y, jc = blockIdx.x;
    int t = threadIdx.x;
    int r = t >> 4, c = t & 15;
    int row = jc * 16 + r;
    const float4* wr = (const float4*)(Wg + (size_t)row * (2 * DD) + DD);
    const float4* mv = (const float4*)(ctx + (size_t)b * DD);
    float acc = 0.f;
#pragma unroll
    for (int it = 0; it < 8; ++it) {
        int k4 = c + it * 16;
        float4 w = wr[k4], m = mv[k4];
        acc = fmaf(w.x, m.x, acc); acc = fmaf(w.y, m.y, acc);
        acc = fmaf(w.z, m.z, acc); acc = fmaf(w.w, m.w, acc);
    }
#pragma unroll
    for (int m = 1; m < 16; m <<= 1) acc += __shfl_xor(acc, m);
    if (c == 0) ctxb[(size_t)b * DD + row] = acc + bgt[row];
}

// ---------------- K5: bf16 MFMA gate GEMM + fused epilogue ----------------
// BM=128, BN=512 (full width -> A staged once). 512 threads, 8 waves (2Mx4N).
#define BK 32
__global__ __launch_bounds__(512, 2) void k5_gemm_fused(
    const float* __restrict__ hs, const float* __restrict__ Wg,
    const float* __restrict__ ctx, const float* __restrict__ ctxb,
    float* __restrict__ outF) {
    __shared__ short At[128][BK];
    __shared__ short Bt[512][BK];
    __shared__ float ctxLds[DD];
    __shared__ float ctxbLds[DD];

    int bm = blockIdx.x;               // 0..255, rows bm*128
    int t = threadIdx.x;
    int wv = t >> 6, lane = t & 63, ln = lane & 15, kg = lane >> 4;
    int wm = (wv >> 2) * 64, wn = (wv & 3) * 128;
    int bbatch = bm >> 4;

    ctxLds[t]  = ctx[(size_t)bbatch * DD + t];
    ctxbLds[t] = ctxb[(size_t)bbatch * DD + t];

    float4 pf[5][2];
    auto gload = [&](int kt) {
        {   // A: unit u = t: row = u>>2 (0..127), slot = u&3
            const float* src = hs + (size_t)(bm * 128 + (t >> 2)) * DD + kt * BK + (t & 3) * 8;
            pf[0][0] = ((const float4*)src)[0];
            pf[0][1] = ((const float4*)src)[1];
        }
#pragma unroll
        for (int i = 0; i < 4; ++i) {   // B: u = t + i*512: row = u>>2 (0..511)
            int u = t + i * 512;
            const float* src = Wg + (size_t)(u >> 2) * (2 * DD) + kt * BK + (u & 3) * 8;
            pf[1 + i][0] = ((const float4*)src)[0];
            pf[1 + i][1] = ((const float4*)src)[1];
        }
    };
    auto cvt1 = [&](float4 lo, float4 hi) {
        s16x8 cv;
        cv[0] = f2bf(lo.x); cv[1] = f2bf(lo.y); cv[2] = f2bf(lo.z); cv[3] = f2bf(lo.w);
        cv[4] = f2bf(hi.x); cv[5] = f2bf(hi.y); cv[6] = f2bf(hi.z); cv[7] = f2bf(hi.w);
        return cv;
    };
    auto cvtwrite = [&]() {
        {
            int row = t >> 2, slot = t & 3;
            int sl = slot ^ ((row >> 1) & 3);
            *(s16x8*)(&At[row][sl * 8]) = cvt1(pf[0][0], pf[0][1]);
        }
#pragma unroll
        for (int i = 0; i < 4; ++i) {
            int u = t + i * 512;
            int row = u >> 2, slot = u & 3;
            int sl = slot ^ ((row >> 1) & 3);
            *(s16x8*)(&Bt[row][sl * 8]) = cvt1(pf[1 + i][0], pf[1 + i][1]);
        }
    };

    f32x4 accv[4][8];
#pragma unroll
    for (int i = 0; i < 4; ++i)
#pragma unroll
        for (int j = 0; j < 8; ++j) accv[i][j] = (f32x4){0.f, 0.f, 0.f, 0.f};

    gload(0);
    for (int kt = 0; kt < DD / BK; ++kt) {
        __syncthreads();
        cvtwrite();
        if (kt + 1 < DD / BK) gload(kt + 1);
        __syncthreads();
        s16x8 af[4], bfr[8];
#pragma unroll
        for (int mi = 0; mi < 4; ++mi) {
            int row = wm + mi * 16 + ln;
            int sl = kg ^ ((row >> 1) & 3);
            af[mi] = *(const s16x8*)&At[row][sl * 8];
        }
#pragma unroll
        for (int nj = 0; nj < 8; ++nj) {
            int row = wn + nj * 16 + ln;
            int sl = kg ^ ((row >> 1) & 3);
            bfr[nj] = *(const s16x8*)&Bt[row][sl * 8];
        }
#pragma unroll
        for (int mi = 0; mi < 4; ++mi)
#pragma unroll
            for (int nj = 0; nj < 8; ++nj)
                accv[mi][nj] = __builtin_amdgcn_mfma_f32_16x16x32_bf16(
                    af[mi], bfr[nj], accv[mi][nj], 0, 0, 0);
    }

    // epilogue: gate = sigmoid(acc + ctxb); fused = g*h + (1-g)*ctx
#pragma unroll
    for (int mi = 0; mi < 4; ++mi)
#pragma unroll
        for (int nj = 0; nj < 8; ++nj)
#pragma unroll
            for (int r = 0; r < 4; ++r) {
                int ri = wm + mi * 16 + kg * 4 + r;
                int ci = wn + nj * 16 + ln;
                size_t grow = (size_t)bm * 128 + ri;
                float logit = accv[mi][nj][r] + ctxbLds[ci];
                float g = __builtin_amdgcn_rcpf(1.0f + __expf(-logit));
                float h = hs[grow * DD + ci];
                float cx = ctxLds[ci];
                outF[grow * DD + ci] = g * h + (1.0f - g) * cx;
            }
}

// ---------------- launch ----------------
extern "C" void kernel_launch(void* const* d_in, const int* in_sizes, int n_in,
                              void* d_out, int out_size, void* d_ws, size_t ws_size,
                              hipStream_t stream) {
    const float* hs   = (const float*)d_in[0];
    const float* docs = (const float*)d_in[1];
    const float* Wq   = (const float*)d_in[2];
    const float* bq   = (const float*)d_in[3];
    const float* Wg   = (const float*)d_in[4];
    const float* bgt  = (const float*)d_in[5];
    float* outp = (float*)d_out;
    float* ws = (float*)d_ws;

    float* partial = ws;                               // 32*16*512 = 262144
    float* mean    = partial + 32 * BB * DD;           // 8192
    float* qtmp    = mean + BB * DD;                   // 8192
    float* qv      = qtmp + BB * DD;                   // 8192
    float* ctx     = qv + BB * DD;                     // 8192
    float* ctxb    = ctx + BB * DD;                    // 8192
    float* cand_s  = ctxb + BB * DD;                   // 1563*80 = 125040
    int*   cand_i  = (int*)(cand_s + NBLK3 * BB * TOPK);

    k1_mean_partial<<<dim3(32, BB), 128, 0, stream>>>(hs, partial);
    k1b_mean_reduce<<<dim3(4, BB), 128, 0, stream>>>(partial, mean);
    k2a_q_gemv<<<dim3(32, BB), 256, 0, stream>>>(mean, Wq, bq, qtmp);
    k2b_q_norm<<<BB, 256, 0, stream>>>(qtmp, qv);
    k3_scores<<<NBLK3, 256, 0, stream>>>(docs, qv, cand_s, cand_i);
    k4a_topk_ctx<<<BB, 256, 0, stream>>>(docs, cand_s, cand_i, ctx, outp);
    k4b_ctxb_gemv<<<dim3(32, BB), 256, 0, stream>>>(ctx, Wg, bgt, ctxb);
    k5_gemm_fused<<<256, 512, 0, stream>>>(hs, Wg, ctx, ctxb,
                                           outp + 2 * BB * TOPK);
}

// Round 3
// 255.998 us; speedup vs baseline: 1.3894x; 1.2077x over previous
//
#include <hip/hip_runtime.h>
#include <hip/hip_bf16.h>
#include <math.h>

#define BB 16
#define SS 2048
#define DD 512
#define NDOCS 200000
#define TOPK 5
#define EPSN 1e-12f
#define NEG_INF (-3.0e38f)

#define TILE_N 128
#define KC 32
#define NCHUNK (DD / KC)                          // 16
#define NBLK3 ((NDOCS + TILE_N - 1) / TILE_N)     // 1563

typedef short s16x8 __attribute__((ext_vector_type(8)));
typedef float f32x4 __attribute__((ext_vector_type(4)));

__device__ __forceinline__ short f2bf(float f) {
    __bf16 b = (__bf16)f;
    short s;
    __builtin_memcpy(&s, &b, 2);
    return s;
}

__device__ __forceinline__ void gload_lds16(const void* g, void* l) {
    __builtin_amdgcn_global_load_lds(
        (const __attribute__((address_space(1))) void*)g,
        (__attribute__((address_space(3))) void*)l, 16, 0, 0);
}

// ---------------- K1: partial mean pool: partial[32][16][512] ----------------
__global__ __launch_bounds__(128) void k1_mean_partial(
    const float* __restrict__ hs, float* __restrict__ partial) {
    int b = blockIdx.y, sc = blockIdx.x;
    int t = threadIdx.x;
    const float4* src = (const float4*)(hs + (size_t)(b * SS + sc * 64) * DD);
    float4 acc = {0.f, 0.f, 0.f, 0.f};
    for (int s = 0; s < 64; ++s) {
        float4 v = src[(size_t)s * 128 + t];
        acc.x += v.x; acc.y += v.y; acc.z += v.z; acc.w += v.w;
    }
    ((float4*)partial)[(size_t)(sc * BB + b) * 128 + t] = acc;
}

// ---------------- K1b: reduce partials -> mean[16][512] ----------------
__global__ __launch_bounds__(128) void k1b_mean_reduce(
    const float* __restrict__ partial, float* __restrict__ mean) {
    int b = blockIdx.y, jc = blockIdx.x;
    int j = jc * 128 + threadIdx.x;
    float s = 0.f;
    for (int c = 0; c < 32; ++c) s += partial[(size_t)(c * BB + b) * DD + j];
    mean[(size_t)b * DD + j] = s * (1.0f / 2048.0f);
}

// ---------------- K2a: qtmp[b][j] = mean[b] . Wq[j] + bq[j] ----------------
__global__ __launch_bounds__(256) void k2a_q_gemv(
    const float* __restrict__ mean, const float* __restrict__ Wq,
    const float* __restrict__ bq, float* __restrict__ qtmp) {
    int b = blockIdx.y, jc = blockIdx.x;
    int t = threadIdx.x;
    int r = t >> 4, c = t & 15;
    int row = jc * 16 + r;
    const float4* wr = (const float4*)(Wq + (size_t)row * DD);
    const float4* mv = (const float4*)(mean + (size_t)b * DD);
    float acc = 0.f;
#pragma unroll
    for (int it = 0; it < 8; ++it) {
        int k4 = c + it * 16;
        float4 w = wr[k4], m = mv[k4];
        acc = fmaf(w.x, m.x, acc); acc = fmaf(w.y, m.y, acc);
        acc = fmaf(w.z, m.z, acc); acc = fmaf(w.w, m.w, acc);
    }
#pragma unroll
    for (int m = 1; m < 16; m <<= 1) acc += __shfl_xor(acc, m);
    if (c == 0) qtmp[(size_t)b * DD + row] = acc + bq[row];
}

// ---------------- K2b: l2-normalize qtmp -> qv ----------------
__global__ __launch_bounds__(256) void k2b_q_norm(
    const float* __restrict__ qtmp, float* __restrict__ qv) {
    int b = blockIdx.x, t = threadIdx.x;
    __shared__ float red[4];
    float a0 = qtmp[(size_t)b * DD + t];
    float a1 = qtmp[(size_t)b * DD + t + 256];
    float ss = a0 * a0 + a1 * a1;
#pragma unroll
    for (int m = 1; m < 64; m <<= 1) ss += __shfl_xor(ss, m);
    if ((t & 63) == 0) red[t >> 6] = ss;
    __syncthreads();
    float inv = 1.0f / fmaxf(sqrtf(red[0] + red[1] + red[2] + red[3]), EPSN);
    qv[(size_t)b * DD + t] = a0 * inv;
    qv[(size_t)b * DD + t + 256] = a1 * inv;
}

// ---------------- K2c: split qv into bf16 hi/lo, swizzled layout ----------------
// qsplit shorts: hi at [b*512 + phys*8 + j], lo at [8192 + same], phys=(k>>3)^(b&7)
__global__ __launch_bounds__(256) void k2c_qsplit(
    const float* __restrict__ qv, short* __restrict__ qsplit) {
    int b = blockIdx.x, t = threadIdx.x;
#pragma unroll
    for (int kk = 0; kk < 2; ++kk) {
        int k = t + kk * 256;
        float f = qv[(size_t)b * DD + k];
        unsigned u = __float_as_uint(f);
        short hi = (short)(u >> 16);
        float r = f - __uint_as_float(u & 0xFFFF0000u);
        short lo = f2bf(r);
        int slot = k >> 3, j = k & 7;
        int off = b * 512 + ((slot ^ (b & 7)) << 3) + j;
        qsplit[off] = hi;
        qsplit[8192 + off] = lo;
    }
}

// ---------------- K3: MFMA corpus scan + per-block top-5 ----------------
// 256 thr (4 waves), tile 128 docs. LDS: doc dbuf 2x16KB + q hi/lo 32KB = 64KB.
__global__ __launch_bounds__(256) void k3_scores(
    const float* __restrict__ docs, const short* __restrict__ qsplit,
    float* __restrict__ cand_s, int* __restrict__ cand_i) {
    __shared__ float4 Et[2][TILE_N * 8];   // [buf][n*8 + physslot]
    __shared__ short qS[2 * 8192];         // hi plane, lo plane

    int t = threadIdx.x;
    int w = t >> 6, lane = t & 63;
    int bq = lane & 15, kg = lane >> 4;
    int blk = blockIdx.x;
    long tileBase = (long)blk * TILE_N;

    // ---- stage q table (32KB) once, linear copy (swizzle pre-baked by K2c)
#pragma unroll
    for (int j = 0; j < 8; ++j) {
        int u = ((w * 8 + j) << 6) + lane;
        gload_lds16(qsplit + (size_t)u * 8, (void*)&qS[(w * 8 + j) * 512]);
    }

    // ---- doc tile staging: chunk c = 32 dims, 8 slots of 16B per row
    auto stage = [&](int c, int buf) {
#pragma unroll
        for (int j = 0; j < 4; ++j) {
            int u = ((w * 4 + j) << 6) + lane;
            int n = u >> 3, slot = u & 7;
            int k4src = slot ^ (n & 7);
            long row = tileBase + n;
            if (row > NDOCS - 1) row = NDOCS - 1;
            gload_lds16(docs + row * (long)DD + c * KC + k4src * 4,
                        (void*)&Et[buf][(w * 4 + j) * 64]);
        }
    };

    f32x4 acc[2], n1[2], n2[2];
#pragma unroll
    for (int f = 0; f < 2; ++f) {
        acc[f] = (f32x4){0.f, 0.f, 0.f, 0.f};
        n1[f]  = (f32x4){0.f, 0.f, 0.f, 0.f};
        n2[f]  = (f32x4){0.f, 0.f, 0.f, 0.f};
    }

    stage(0, 0);
    for (int c = 0; c < NCHUNK; ++c) {
        __syncthreads();                       // stage(c) + q drained
        if (c + 1 < NCHUNK) stage(c + 1, (c + 1) & 1);

        int qphys = ((c * 4 + kg) ^ (bq & 7)) << 3;
        s16x8 qh = *(const s16x8*)&qS[bq * 512 + qphys];
        s16x8 ql = *(const s16x8*)&qS[8192 + bq * 512 + qphys];

        const float4* Eb = &Et[c & 1][0];
#pragma unroll
        for (int f = 0; f < 2; ++f) {
            int d = (w << 5) + (f << 4) + bq;     // doc row in tile (A row=bq)
            int base = d << 3;
            float4 e0 = Eb[base + ((kg * 2) ^ (d & 7))];
            float4 e1 = Eb[base + ((kg * 2 + 1) ^ (d & 7))];
            float ef[8] = {e0.x, e0.y, e0.z, e0.w, e1.x, e1.y, e1.z, e1.w};
            s16x8 ah, al;
#pragma unroll
            for (int i = 0; i < 8; ++i) {
                unsigned u = __float_as_uint(ef[i]);
                ah[i] = (short)(u >> 16);
                al[i] = f2bf(ef[i] - __uint_as_float(u & 0xFFFF0000u));
            }
            acc[f] = __builtin_amdgcn_mfma_f32_16x16x32_bf16(ah, qh, acc[f], 0, 0, 0);
            acc[f] = __builtin_amdgcn_mfma_f32_16x16x32_bf16(ah, ql, acc[f], 0, 0, 0);
            acc[f] = __builtin_amdgcn_mfma_f32_16x16x32_bf16(al, qh, acc[f], 0, 0, 0);
            n1[f]  = __builtin_amdgcn_mfma_f32_16x16x32_bf16(ah, ah, n1[f], 0, 0, 0);
            n2[f]  = __builtin_amdgcn_mfma_f32_16x16x32_bf16(ah, al, n2[f], 0, 0, 0);
        }
    }

    // ---- scale by 1/||e|| (diag of norm frags) and dump scoreboard
    float* Sb = (float*)&Et[0][0];   // [16 batches][128 docs], 8KB
#pragma unroll
    for (int f = 0; f < 2; ++f) {
        int rd = bq & 3;
        float nd = n1[f][rd] + 2.0f * n2[f][rd];        // valid on diag lanes
        float invn = 1.0f / fmaxf(sqrtf(nd), EPSN);
#pragma unroll
        for (int r = 0; r < 4; ++r) {
            float iv = __shfl(invn, kg * 20 + r);        // diag lane kg*16+kg*4+r
            int n = (w << 5) + (f << 4) + (kg << 2) + r;
            Sb[bq * TILE_N + n] = acc[f][r] * iv;        // col=bq is the batch
        }
    }
    __syncthreads();

    // ---- per-block top-5 per batch (wave handles 4 batches)
    for (int jj = 0; jj < 4; ++jj) {
        int b = w * 4 + jj;
        float v[2]; int nn[2];
#pragma unroll
        for (int m = 0; m < 2; ++m) {
            int n = lane + m * 64;
            nn[m] = n;
            v[m] = (tileBase + n < NDOCS) ? Sb[b * TILE_N + n] : NEG_INF;
        }
        for (int r = 0; r < TOPK; ++r) {
            float bv = v[0]; int bi = nn[0];
            if (v[1] > bv || (v[1] == bv && nn[1] < bi)) { bv = v[1]; bi = nn[1]; }
#pragma unroll
            for (int mm = 1; mm < 64; mm <<= 1) {
                float ov = __shfl_xor(bv, mm);
                int   oi = __shfl_xor(bi, mm);
                if (ov > bv || (ov == bv && oi < bi)) { bv = ov; bi = oi; }
            }
            if (lane == 0) {
                cand_s[((long)blk * BB + b) * TOPK + r] = bv;
                cand_i[((long)blk * BB + b) * TOPK + r] = (int)(tileBase + bi);
            }
#pragma unroll
            for (int m = 0; m < 2; ++m)
                if (nn[m] == bi) v[m] = NEG_INF;
        }
    }
}

// ---------------- K4a: merge top-5, softmax, context, outputs ----------------
__global__ __launch_bounds__(256) void k4a_topk_ctx(
    const float* __restrict__ docs, const float* __restrict__ cand_s,
    const int* __restrict__ cand_i, float* __restrict__ ctx,
    float* __restrict__ outp) {
    int b = blockIdx.x, t = threadIdx.x;
    __shared__ float sv[256];
    __shared__ int   si[256];
    __shared__ float topv[TOPK];
    __shared__ int   topi[TOPK];
    __shared__ float red[4];
    __shared__ float nrm5[TOPK];
    __shared__ float wts[TOPK];

    float lv[TOPK]; int li[TOPK];
#pragma unroll
    for (int r = 0; r < TOPK; ++r) { lv[r] = NEG_INF; li[r] = 0x7fffffff; }

    for (int j = t; j < NBLK3 * TOPK; j += 256) {
        int blk = j / TOPK, r = j - blk * TOPK;
        float s = cand_s[(long)blk * (BB * TOPK) + b * TOPK + r];
        int  di = cand_i[(long)blk * (BB * TOPK) + b * TOPK + r];
        if (s > lv[TOPK - 1] || (s == lv[TOPK - 1] && di < li[TOPK - 1])) {
            lv[TOPK - 1] = s; li[TOPK - 1] = di;
#pragma unroll
            for (int k = TOPK - 1; k > 0; --k) {
                if (lv[k] > lv[k - 1] || (lv[k] == lv[k - 1] && li[k] < li[k - 1])) {
                    float tv = lv[k]; lv[k] = lv[k - 1]; lv[k - 1] = tv;
                    int   ti = li[k]; li[k] = li[k - 1]; li[k - 1] = ti;
                }
            }
        }
    }

    int p = 0;
    for (int r = 0; r < TOPK; ++r) {
        float hv = (p < TOPK) ? lv[p] : NEG_INF;
        int   hi = (p < TOPK) ? li[p] : 0x7fffffff;
        sv[t] = hv; si[t] = hi;
        __syncthreads();
        for (int off = 128; off > 0; off >>= 1) {
            if (t < off) {
                float ov = sv[t + off]; int oi = si[t + off];
                if (ov > sv[t] || (ov == sv[t] && oi < si[t])) { sv[t] = ov; si[t] = oi; }
            }
            __syncthreads();
        }
        if (t == 0) { topv[r] = sv[0]; topi[r] = si[0]; }
        __syncthreads();
        if (hv == topv[r] && hi == topi[r]) ++p;
        __syncthreads();
    }

    for (int r = 0; r < TOPK; ++r) {
        const float* dr = docs + (size_t)topi[r] * DD;
        float s2 = dr[t] * dr[t] + dr[t + 256] * dr[t + 256];
#pragma unroll
        for (int m = 1; m < 64; m <<= 1) s2 += __shfl_xor(s2, m);
        if ((t & 63) == 0) red[t >> 6] = s2;
        __syncthreads();
        if (t == 0) nrm5[r] = sqrtf(red[0] + red[1] + red[2] + red[3]);
        __syncthreads();
    }

    if (t == 0) {
        float m = topv[0];
        float e[TOPK], s = 0.f;
#pragma unroll
        for (int r = 0; r < TOPK; ++r) { e[r] = expf(topv[r] - m); s += e[r]; }
#pragma unroll
        for (int r = 0; r < TOPK; ++r) wts[r] = e[r] / s;
    }
    __syncthreads();

    for (int j = t; j < DD; j += 256) {
        float c = 0.f;
#pragma unroll
        for (int r = 0; r < TOPK; ++r)
            c += wts[r] * docs[(size_t)topi[r] * DD + j] / fmaxf(nrm5[r], EPSN);
        ctx[(size_t)b * DD + j] = c;
    }

    if (t < TOPK) {
        outp[b * TOPK + t] = topv[t];
        outp[BB * TOPK + b * TOPK + t] = (float)topi[t];
    }
}

// ---------------- K4b: ctxb[b][j] = ctx[b] . Wg[j, 512:1024] + bg[j] --------
__global__ __launch_bounds__(256) void k4b_ctxb_gemv(
    const float* __restrict__ ctx, const float* __restrict__ Wg,
    const float* __restrict__ bgt, float* __restrict__ ctxb) {
    int b = blockIdx.y, jc = blockIdx.x;
    int t = threadIdx.x;
    int r = t >> 4, c = t & 15;
    int row = jc * 16 + r;
    const float4* wr = (const float4*)(Wg + (size_t)row * (2 * DD) + DD);
    const float4* mv = (const float4*)(ctx + (size_t)b * DD);
    float acc = 0.f;
#pragma unroll
    for (int it = 0; it < 8; ++it) {
        int k4 = c + it * 16;
        float4 w = wr[k4], m = mv[k4];
        acc = fmaf(w.x, m.x, acc); acc = fmaf(w.y, m.y, acc);
        acc = fmaf(w.z, m.z, acc); acc = fmaf(w.w, m.w, acc);
    }
#pragma unroll
    for (int m = 1; m < 16; m <<= 1) acc += __shfl_xor(acc, m);
    if (c == 0) ctxb[(size_t)b * DD + row] = acc + bgt[row];
}

// ---------------- K5: bf16 MFMA gate GEMM + fused epilogue ----------------
#define BK 32
__global__ __launch_bounds__(512, 2) void k5_gemm_fused(
    const float* __restrict__ hs, const float* __restrict__ Wg,
    const float* __restrict__ ctx, const float* __restrict__ ctxb,
    float* __restrict__ outF) {
    __shared__ short At[128][BK];
    __shared__ short Bt[512][BK];
    __shared__ float ctxLds[DD];
    __shared__ float ctxbLds[DD];

    int bm = blockIdx.x;
    int t = threadIdx.x;
    int wv = t >> 6, lane = t & 63, ln = lane & 15, kg = lane >> 4;
    int wm = (wv >> 2) * 64, wn = (wv & 3) * 128;
    int bbatch = bm >> 4;

    ctxLds[t]  = ctx[(size_t)bbatch * DD + t];
    ctxbLds[t] = ctxb[(size_t)bbatch * DD + t];

    float4 pf[5][2];
    auto gload = [&](int kt) {
        {
            const float* src = hs + (size_t)(bm * 128 + (t >> 2)) * DD + kt * BK + (t & 3) * 8;
            pf[0][0] = ((const float4*)src)[0];
            pf[0][1] = ((const float4*)src)[1];
        }
#pragma unroll
        for (int i = 0; i < 4; ++i) {
            int u = t + i * 512;
            const float* src = Wg + (size_t)(u >> 2) * (2 * DD) + kt * BK + (u & 3) * 8;
            pf[1 + i][0] = ((const float4*)src)[0];
            pf[1 + i][1] = ((const float4*)src)[1];
        }
    };
    auto cvt1 = [&](float4 lo, float4 hi) {
        s16x8 cv;
        cv[0] = f2bf(lo.x); cv[1] = f2bf(lo.y); cv[2] = f2bf(lo.z); cv[3] = f2bf(lo.w);
        cv[4] = f2bf(hi.x); cv[5] = f2bf(hi.y); cv[6] = f2bf(hi.z); cv[7] = f2bf(hi.w);
        return cv;
    };
    auto cvtwrite = [&]() {
        {
            int row = t >> 2, slot = t & 3;
            int sl = slot ^ ((row >> 1) & 3);
            *(s16x8*)(&At[row][sl * 8]) = cvt1(pf[0][0], pf[0][1]);
        }
#pragma unroll
        for (int i = 0; i < 4; ++i) {
            int u = t + i * 512;
            int row = u >> 2, slot = u & 3;
            int sl = slot ^ ((row >> 1) & 3);
            *(s16x8*)(&Bt[row][sl * 8]) = cvt1(pf[1 + i][0], pf[1 + i][1]);
        }
    };

    f32x4 accv[4][8];
#pragma unroll
    for (int i = 0; i < 4; ++i)
#pragma unroll
        for (int j = 0; j < 8; ++j) accv[i][j] = (f32x4){0.f, 0.f, 0.f, 0.f};

    gload(0);
    for (int kt = 0; kt < DD / BK; ++kt) {
        __syncthreads();
        cvtwrite();
        if (kt + 1 < DD / BK) gload(kt + 1);
        __syncthreads();
        s16x8 af[4], bfr[8];
#pragma unroll
        for (int mi = 0; mi < 4; ++mi) {
            int row = wm + mi * 16 + ln;
            int sl = kg ^ ((row >> 1) & 3);
            af[mi] = *(const s16x8*)&At[row][sl * 8];
        }
#pragma unroll
        for (int nj = 0; nj < 8; ++nj) {
            int row = wn + nj * 16 + ln;
            int sl = kg ^ ((row >> 1) & 3);
            bfr[nj] = *(const s16x8*)&Bt[row][sl * 8];
        }
#pragma unroll
        for (int mi = 0; mi < 4; ++mi)
#pragma unroll
            for (int nj = 0; nj < 8; ++nj)
                accv[mi][nj] = __builtin_amdgcn_mfma_f32_16x16x32_bf16(
                    af[mi], bfr[nj], accv[mi][nj], 0, 0, 0);
    }

#pragma unroll
    for (int mi = 0; mi < 4; ++mi)
#pragma unroll
        for (int nj = 0; nj < 8; ++nj)
#pragma unroll
            for (int r = 0; r < 4; ++r) {
                int ri = wm + mi * 16 + kg * 4 + r;
                int ci = wn + nj * 16 + ln;
                size_t grow = (size_t)bm * 128 + ri;
                float logit = accv[mi][nj][r] + ctxbLds[ci];
                float g = __builtin_amdgcn_rcpf(1.0f + __expf(-logit));
                float h = hs[grow * DD + ci];
                float cx = ctxLds[ci];
                outF[grow * DD + ci] = g * h + (1.0f - g) * cx;
            }
}

// ---------------- launch ----------------
extern "C" void kernel_launch(void* const* d_in, const int* in_sizes, int n_in,
                              void* d_out, int out_size, void* d_ws, size_t ws_size,
                              hipStream_t stream) {
    const float* hs   = (const float*)d_in[0];
    const float* docs = (const float*)d_in[1];
    const float* Wq   = (const float*)d_in[2];
    const float* bq   = (const float*)d_in[3];
    const float* Wg   = (const float*)d_in[4];
    const float* bgt  = (const float*)d_in[5];
    float* outp = (float*)d_out;
    float* ws = (float*)d_ws;

    float* partial = ws;                               // 32*16*512
    float* mean    = partial + 32 * BB * DD;
    float* qtmp    = mean + BB * DD;
    float* qv      = qtmp + BB * DD;
    float* ctx     = qv + BB * DD;
    float* ctxb    = ctx + BB * DD;
    float* cand_s  = ctxb + BB * DD;                   // NBLK3*16*5
    int*   cand_i  = (int*)(cand_s + NBLK3 * BB * TOPK);
    short* qsplit  = (short*)(cand_i + NBLK3 * BB * TOPK);  // 16384 shorts

    k1_mean_partial<<<dim3(32, BB), 128, 0, stream>>>(hs, partial);
    k1b_mean_reduce<<<dim3(4, BB), 128, 0, stream>>>(partial, mean);
    k2a_q_gemv<<<dim3(32, BB), 256, 0, stream>>>(mean, Wq, bq, qtmp);
    k2b_q_norm<<<BB, 256, 0, stream>>>(qtmp, qv);
    k2c_qsplit<<<BB, 256, 0, stream>>>(qv, qsplit);
    k3_scores<<<NBLK3, 256, 0, stream>>>(docs, qsplit, cand_s, cand_i);
    k4a_topk_ctx<<<BB, 256, 0, stream>>>(docs, cand_s, cand_i, ctx, outp);
    k4b_ctxb_gemv<<<dim3(32, BB), 256, 0, stream>>>(ctx, Wg, bgt, ctxb);
    k5_gemm_fused<<<256, 512, 0, stream>>>(hs, Wg, ctx, ctxb,
                                           outp + 2 * BB * TOPK);
}